// Round 4
// baseline (314.615 us; speedup 1.0000x reference)
//
#include <hip/hip_runtime.h>

#define T_DIM 720
#define B_DIM 50000
#define S_DIM 7

#define OFF_SEAS (T_DIM * B_DIM)                  /* 36,000,000 */
#define SEAS_ROWS (S_DIM + 1 + (T_DIM - 1))       /* 727 */
#define OFF_MSLD (OFF_SEAS + SEAS_ROWS * B_DIM)   /* 72,350,000 */
#define N_MSLD (T_DIM - 2)                        /* 718 */

#define NPAIR 25000
#define NBLK ((NPAIR + 63) / 64)                  /* 391 one-wave blocks */
#define NW NBLK

typedef float v2f __attribute__((ext_vector_type(2)));

// ---- one series' recurrence update (all indices compile-time) ----
#define STEP_ONE(XV, POS, SFX)                                                 \
  float nl##SFX = fmaf(lsm##SFX, __fdividef(XV, buf##SFX[POS]),                \
                       olm##SFX * lev##SFX);                                   \
  float ll##SFX = __logf(nl##SFX);                                             \
  float ld##SFX = ll##SFX - llev##SFX;                                         \
  float ns##SFX = fmaf(ssm##SFX, __fdividef(XV, nl##SFX),                      \
                       osm##SFX * buf##SFX[POS]);                              \
  buf##SFX[POS] = ns##SFX;                                                     \
  float dd##SFX = ld##SFX - pld##SFX;                                          \
  pld##SFX = ld##SFX;                                                          \
  llev##SFX = ll##SFX;                                                         \
  lev##SFX = nl##SFX;

// ---- one step for the pair of series ----
#define ESRNN_STEP(QB, POS)                                                    \
  {                                                                            \
    v2f x = QB[POS];                                                           \
    STEP_ONE(x.x, POS, 0)                                                      \
    STEP_ONE(x.y, POS, 1)                                                      \
    if (valid) {                                                               \
      v2f lv;                                                                  \
      lv.x = nl0;                                                              \
      lv.y = nl1;                                                              \
      __builtin_nontemporal_store(lv, (v2f*)&levs_out[t * B_DIM + col]);       \
      v2f sv;                                                                  \
      sv.x = ns0;                                                              \
      sv.y = ns1;                                                              \
      __builtin_nontemporal_store(sv, (v2f*)&seas_out[(t + 7) * B_DIM + col]); \
    }                                                                          \
    sqv[POS] = (valid && t >= 2) ? (dd0 * dd0 + dd1 * dd1) : 0.0f;             \
    ++t;                                                                       \
  }

// ---- prefetch group G (rows 1+7G .. 7+7G, clamped) into QB, pin in regs ----
#define PREFETCH(QB, G)                                                        \
  {                                                                            \
    int tp = 1 + 7 * (G);                                                      \
    _Pragma("unroll") for (int j = 0; j < 7; ++j) {                            \
      int r = tp + j;                                                          \
      r = r > 719 ? 719 : r;                                                   \
      QB[j] = *(const v2f*)&train[r * B_DIM + col];                            \
    }                                                                          \
    asm volatile("" : "+v"(QB[0]), "+v"(QB[1]), "+v"(QB[2]), "+v"(QB[3]),      \
                      "+v"(QB[4]), "+v"(QB[5]), "+v"(QB[6]));                  \
  }

// ---- wave-reduce sqv[J], store per-wave partial ----
#define ESRNN_REDUCE(J)                                                        \
  {                                                                            \
    float v = sqv[J];                                                          \
    _Pragma("unroll") for (int off = 1; off < 64; off <<= 1)                   \
        v += __shfl_xor(v, off, 64);                                           \
    int row = tb + (J)-2;                                                      \
    if (lane == 0 && row >= 0) partial[row * NW + wid] = v;                    \
  }

#define ESRNN_GROUP(QB, QP)                                                    \
  {                                                                            \
    PREFETCH(QP, g + 2)                                                        \
    int tb = t;                                                                \
    ESRNN_STEP(QB, 0)                                                          \
    ESRNN_STEP(QB, 1)                                                          \
    ESRNN_STEP(QB, 2)                                                          \
    ESRNN_STEP(QB, 3)                                                          \
    ESRNN_STEP(QB, 4)                                                          \
    ESRNN_STEP(QB, 5)                                                          \
    ESRNN_STEP(QB, 6)                                                          \
    ESRNN_REDUCE(0)                                                            \
    ESRNN_REDUCE(1)                                                            \
    ESRNN_REDUCE(2)                                                            \
    ESRNN_REDUCE(3)                                                            \
    ESRNN_REDUCE(4)                                                            \
    ESRNN_REDUCE(5)                                                            \
    ESRNN_REDUCE(6)                                                            \
    ++g;                                                                       \
  }

__global__ __launch_bounds__(64) void esrnn_main(
    const float* __restrict__ train,        // (720, B)
    const float* __restrict__ lev_sms,      // (B,)
    const float* __restrict__ seas_sms,     // (B,)
    const float* __restrict__ init_seas_in, // (B, 7)
    float* __restrict__ levs_out,           // (720, B)
    float* __restrict__ seas_out,           // (727, B)
    float* __restrict__ partial)            // (718, NW) per-wave partials
{
  int p = blockIdx.x * 64 + threadIdx.x;  // pair index
  bool valid = (p < NPAIR);
  int pc = valid ? p : (NPAIR - 1);
  int col = 2 * pc;  // first series of the pair
  int lane = threadIdx.x;
  int wid = blockIdx.x;

  v2f lsm2 = *(const v2f*)&lev_sms[col];
  v2f ssm2 = *(const v2f*)&seas_sms[col];
  float lsm0 = 1.0f / (1.0f + __expf(-lsm2.x));
  float lsm1 = 1.0f / (1.0f + __expf(-lsm2.y));
  float ssm0 = 1.0f / (1.0f + __expf(-ssm2.x));
  float ssm1 = 1.0f / (1.0f + __expf(-ssm2.y));
  float olm0 = 1.0f - lsm0, olm1 = 1.0f - lsm1;
  float osm0 = 1.0f - ssm0, osm1 = 1.0f - ssm1;

  float is0[7], is1[7];
#pragma unroll
  for (int j = 0; j < 7; ++j) {
    is0[j] = __expf(init_seas_in[col * 7 + j]);
    is1[j] = __expf(init_seas_in[col * 7 + 7 + j]);
  }

  v2f x0v = *(const v2f*)&train[col];
  float lev0 = __fdividef(x0v.x, is0[0]);
  float lev1 = __fdividef(x0v.y, is1[0]);

  if (valid) {
    v2f lv;
    lv.x = lev0;
    lv.y = lev1;
    __builtin_nontemporal_store(lv, (v2f*)&levs_out[col]);
#pragma unroll
    for (int j = 0; j < 7; ++j) {
      v2f sv;
      sv.x = is0[j];
      sv.y = is1[j];
      __builtin_nontemporal_store(sv, (v2f*)&seas_out[j * B_DIM + col]);
    }
    v2f s7;
    s7.x = is0[0];
    s7.y = is1[0];
    __builtin_nontemporal_store(s7, (v2f*)&seas_out[7 * B_DIM + col]);
  }

  float buf0[7], buf1[7];
#pragma unroll
  for (int j = 0; j < 6; ++j) {
    buf0[j] = is0[j + 1];
    buf1[j] = is1[j + 1];
  }
  buf0[6] = is0[0];
  buf1[6] = is1[0];

  float llev0 = __logf(lev0), llev1 = __logf(lev1);
  float pld0 = 0.0f, pld1 = 0.0f;

  v2f xa[7], xb[7], xc[7];
  float sqv[7];
  int g = 0;
  int t = 1;
  PREFETCH(xa, 0)
  PREFETCH(xb, 1)

  // 102 groups = 34 x 3-phase (buffers rotate a,b,c; prefetch 2 ahead)
  for (int k = 0; k < 34; ++k) {
    ESRNN_GROUP(xa, xc)
    ESRNN_GROUP(xb, xa)
    ESRNN_GROUP(xc, xb)
  }

  // tail: t = 715..719, group 102 lives in xa (102 % 3 == 0)
  {
    int tb = t;
    ESRNN_STEP(xa, 0)
    ESRNN_STEP(xa, 1)
    ESRNN_STEP(xa, 2)
    ESRNN_STEP(xa, 3)
    ESRNN_STEP(xa, 4)
    ESRNN_REDUCE(0)
    ESRNN_REDUCE(1)
    ESRNN_REDUCE(2)
    ESRNN_REDUCE(3)
    ESRNN_REDUCE(4)
  }
}

__global__ __launch_bounds__(64) void esrnn_reduce2(
    const float* __restrict__ partial, float* __restrict__ msld) {
  int row = blockIdx.x;  // 0..717
  int lane = threadIdx.x;
  float s = 0.0f;
  for (int i = lane; i < NW; i += 64) s += partial[row * NW + i];
#pragma unroll
  for (int off = 1; off < 64; off <<= 1) s += __shfl_xor(s, off, 64);
  if (lane == 0) msld[row] = s * (1.0f / (float)B_DIM);
}

extern "C" void kernel_launch(void* const* d_in, const int* in_sizes, int n_in,
                              void* d_out, int out_size, void* d_ws,
                              size_t ws_size, hipStream_t stream) {
  const float* train = (const float*)d_in[0];
  const float* lev_sms = (const float*)d_in[1];
  const float* seas_sms = (const float*)d_in[2];
  const float* init_seas = (const float*)d_in[3];

  float* out = (float*)d_out;
  float* levs = out;
  float* seas = out + OFF_SEAS;
  float* msld = out + OFF_MSLD;
  float* partial = (float*)d_ws;  // 718*391*4 ~= 1.12 MB

  esrnn_main<<<NBLK, 64, 0, stream>>>(train, lev_sms, seas_sms, init_seas,
                                      levs, seas, partial);
  esrnn_reduce2<<<N_MSLD, 64, 0, stream>>>(partial, msld);
}

// Round 5
// 175.072 us; speedup vs baseline: 1.7971x; 1.7971x over previous
//
#include <hip/hip_runtime.h>

#define T_DIM 720
#define B_DIM 50000

#define OFF_SEAS (T_DIM * B_DIM)                  /* 36,000,000 */
#define SEAS_ROWS 727
#define OFF_MSLD (OFF_SEAS + SEAS_ROWS * B_DIM)   /* 72,350,000 */
#define N_MSLD 718

#define NBLK 782                                  /* ceil(50000/64) 1-wave blocks */
#define NW NBLK

// Wave64 sum via DPP (VALU-only, no DS): row_shr 1/2/4/8 then row_bcast 15/31.
// Total lands in lane 63. old=0 is the add-identity for masked-off lanes.
__device__ __forceinline__ float dpp_sum64(float v) {
#define DPP_ADD_STAGE(CTRL, RMASK)                                             \
  v += __int_as_float(__builtin_amdgcn_update_dpp(0, __float_as_int(v),        \
                                                  CTRL, RMASK, 0xf, false));
  DPP_ADD_STAGE(0x111, 0xf)  // row_shr:1
  DPP_ADD_STAGE(0x112, 0xf)  // row_shr:2
  DPP_ADD_STAGE(0x114, 0xf)  // row_shr:4
  DPP_ADD_STAGE(0x118, 0xf)  // row_shr:8
  DPP_ADD_STAGE(0x142, 0xa)  // row_bcast:15 -> rows 1,3
  DPP_ADD_STAGE(0x143, 0xc)  // row_bcast:31 -> rows 2,3
#undef DPP_ADD_STAGE
  return v;
}

// One recurrence step. POS compile-time so buf/queues stay in registers.
#define ESRNN_STEP(QB, POS)                                                    \
  {                                                                            \
    float x = QB[POS];                                                         \
    float s = buf[POS];                                                        \
    float nl = fmaf(lsm, __fdividef(x, s), olm * lev);                         \
    float ll = __logf(nl);                                                     \
    float ld = ll - llev;                                                      \
    float ns = fmaf(ssm, __fdividef(x, nl), osm * s);                          \
    buf[POS] = ns;                                                             \
    if (valid) {                                                               \
      __builtin_nontemporal_store(nl, &levs_out[t * B_DIM + b]);               \
      __builtin_nontemporal_store(ns, &seas_out[(t + 7) * B_DIM + b]);         \
    }                                                                          \
    float d = ld - pld;                                                        \
    float sq = (valid && t >= 2) ? d * d : 0.0f;                               \
    float tot = dpp_sum64(sq);                                                 \
    if (lane == 63 && t >= 2) partial[(t - 2) * NW + wid] = tot;               \
    pld = ld;                                                                  \
    llev = ll;                                                                 \
    lev = nl;                                                                  \
    ++t;                                                                       \
  }

// Prefetch group G (rows 1+7G .. 7+7G, clamped) into QB; pin in registers.
#define PREFETCH(QB, G)                                                        \
  {                                                                            \
    int tp = 1 + 7 * (G);                                                      \
    _Pragma("unroll") for (int j = 0; j < 7; ++j) {                            \
      int r = tp + j;                                                          \
      r = r > 719 ? 719 : r;                                                   \
      QB[j] = train[r * B_DIM + bc];                                           \
    }                                                                          \
    asm volatile("" : "+v"(QB[0]), "+v"(QB[1]), "+v"(QB[2]), "+v"(QB[3]),      \
                      "+v"(QB[4]), "+v"(QB[5]), "+v"(QB[6]));                  \
  }

#define ESRNN_GROUP(QB, QP)                                                    \
  {                                                                            \
    PREFETCH(QP, g + 2)                                                        \
    ESRNN_STEP(QB, 0)                                                          \
    ESRNN_STEP(QB, 1)                                                          \
    ESRNN_STEP(QB, 2)                                                          \
    ESRNN_STEP(QB, 3)                                                          \
    ESRNN_STEP(QB, 4)                                                          \
    ESRNN_STEP(QB, 5)                                                          \
    ESRNN_STEP(QB, 6)                                                          \
    ++g;                                                                       \
  }

__global__ __launch_bounds__(64) void esrnn_main(
    const float* __restrict__ train,        // (720, B)
    const float* __restrict__ lev_sms,      // (B,)
    const float* __restrict__ seas_sms,     // (B,)
    const float* __restrict__ init_seas_in, // (B, 7)
    float* __restrict__ levs_out,           // (720, B)
    float* __restrict__ seas_out,           // (727, B)
    float* __restrict__ partial)            // (718, NW) per-wave partials
{
  int b = blockIdx.x * 64 + threadIdx.x;
  bool valid = (b < B_DIM);
  int bc = valid ? b : (B_DIM - 1);
  int lane = threadIdx.x;
  int wid = blockIdx.x;

  float lsm = 1.0f / (1.0f + __expf(-lev_sms[bc]));
  float ssm = 1.0f / (1.0f + __expf(-seas_sms[bc]));
  float olm = 1.0f - lsm;
  float osm = 1.0f - ssm;

  float is[7];
#pragma unroll
  for (int j = 0; j < 7; ++j) is[j] = __expf(init_seas_in[bc * 7 + j]);

  float seas0 = is[0];
  float x0 = train[bc];
  float lev = __fdividef(x0, seas0);

  if (valid) {
    __builtin_nontemporal_store(lev, &levs_out[b]);
#pragma unroll
    for (int j = 0; j < 7; ++j)
      __builtin_nontemporal_store(is[j], &seas_out[j * B_DIM + b]);
    __builtin_nontemporal_store(seas0, &seas_out[7 * B_DIM + b]);
  }

  float buf[7];
#pragma unroll
  for (int j = 0; j < 6; ++j) buf[j] = is[j + 1];
  buf[6] = seas0;

  float llev = __logf(lev);
  float pld = 0.0f;

  float xa[7], xb[7], xc[7];
  int g = 0;
  int t = 1;
  PREFETCH(xa, 0)
  PREFETCH(xb, 1)

  // 102 groups = 34 x 3-phase buffer rotation, prefetching 2 groups ahead.
  for (int k = 0; k < 34; ++k) {
    ESRNN_GROUP(xa, xc)
    ESRNN_GROUP(xb, xa)
    ESRNN_GROUP(xc, xb)
  }

  // tail: t = 715..719 in xa (group 102, 102 % 3 == 0), buf pos 0..4
  ESRNN_STEP(xa, 0)
  ESRNN_STEP(xa, 1)
  ESRNN_STEP(xa, 2)
  ESRNN_STEP(xa, 3)
  ESRNN_STEP(xa, 4)
}

__global__ __launch_bounds__(64) void esrnn_reduce2(
    const float* __restrict__ partial, float* __restrict__ msld) {
  int row = blockIdx.x;  // 0..717
  int lane = threadIdx.x;
  float s = 0.0f;
  for (int i = lane; i < NW; i += 64) s += partial[row * NW + i];
  float tot = dpp_sum64(s);
  if (lane == 63) msld[row] = tot * (1.0f / (float)B_DIM);
}

extern "C" void kernel_launch(void* const* d_in, const int* in_sizes, int n_in,
                              void* d_out, int out_size, void* d_ws,
                              size_t ws_size, hipStream_t stream) {
  const float* train = (const float*)d_in[0];
  const float* lev_sms = (const float*)d_in[1];
  const float* seas_sms = (const float*)d_in[2];
  const float* init_seas = (const float*)d_in[3];

  float* out = (float*)d_out;
  float* levs = out;
  float* seas = out + OFF_SEAS;
  float* msld = out + OFF_MSLD;
  float* partial = (float*)d_ws;  // 718*782*4 ~= 2.25 MB

  esrnn_main<<<NBLK, 64, 0, stream>>>(train, lev_sms, seas_sms, init_seas,
                                      levs, seas, partial);
  esrnn_reduce2<<<N_MSLD, 64, 0, stream>>>(partial, msld);
}

// Round 6
// 165.554 us; speedup vs baseline: 1.9004x; 1.0575x over previous
//
#include <hip/hip_runtime.h>

#define T_DIM 720
#define B_DIM 50000

#define OFF_SEAS (T_DIM * B_DIM)                  /* 36,000,000 */
#define SEAS_ROWS 727
#define OFF_MSLD (OFF_SEAS + SEAS_ROWS * B_DIM)   /* 72,350,000 */
#define N_MSLD 718

#define NBLK 782                                  /* ceil(50000/64) 1-wave blocks */
#define NW NBLK

// Wave64 sum via DPP (VALU-only, no DS): row_shr 1/2/4/8 then row_bcast 15/31.
// Total lands in lane 63. old=0 is the add-identity for masked-off lanes.
__device__ __forceinline__ float dpp_sum64(float v) {
#define DPP_ADD_STAGE(CTRL, RMASK)                                             \
  v += __int_as_float(__builtin_amdgcn_update_dpp(0, __float_as_int(v),        \
                                                  CTRL, RMASK, 0xf, false));
  DPP_ADD_STAGE(0x111, 0xf)  // row_shr:1
  DPP_ADD_STAGE(0x112, 0xf)  // row_shr:2
  DPP_ADD_STAGE(0x114, 0xf)  // row_shr:4
  DPP_ADD_STAGE(0x118, 0xf)  // row_shr:8
  DPP_ADD_STAGE(0x142, 0xa)  // row_bcast:15 -> rows 1,3
  DPP_ADD_STAGE(0x143, 0xc)  // row_bcast:31 -> rows 2,3
#undef DPP_ADD_STAGE
  return v;
}

// One recurrence step. POS compile-time so buf/queues stay in registers.
#define ESRNN_STEP(QB, POS)                                                    \
  {                                                                            \
    float x = QB[POS];                                                         \
    float s = buf[POS];                                                        \
    float nl = fmaf(lsm, __fdividef(x, s), olm * lev);                         \
    float ll = __logf(nl);                                                     \
    float ld = ll - llev;                                                      \
    float ns = fmaf(ssm, __fdividef(x, nl), osm * s);                          \
    buf[POS] = ns;                                                             \
    if (valid) {                                                               \
      __builtin_nontemporal_store(nl, &levs_out[t * B_DIM + b]);               \
      __builtin_nontemporal_store(ns, &seas_out[(t + 7) * B_DIM + b]);         \
    }                                                                          \
    float d = ld - pld;                                                        \
    float sq = (valid && t >= 2) ? d * d : 0.0f;                               \
    float tot = dpp_sum64(sq);                                                 \
    if (lane == 63 && t >= 2) partial[(t - 2) * NW + wid] = tot;               \
    pld = ld;                                                                  \
    llev = ll;                                                                 \
    lev = nl;                                                                  \
    ++t;                                                                       \
  }

// Prefetch group G (rows 1+7G .. 7+7G, clamped) into QB. No pinning: the
// compiler tracks outstanding vmem ops and emits a counted s_waitcnt before
// first use (2 groups later) instead of draining vmcnt(0) here.
#define PREFETCH(QB, G)                                                        \
  {                                                                            \
    int tp = 1 + 7 * (G);                                                      \
    _Pragma("unroll") for (int j = 0; j < 7; ++j) {                            \
      int r = tp + j;                                                          \
      r = r > 719 ? 719 : r;                                                   \
      QB[j] = __builtin_nontemporal_load(&train[r * B_DIM + bc]);              \
    }                                                                          \
  }

#define ESRNN_GROUP(QB, QP)                                                    \
  {                                                                            \
    PREFETCH(QP, g + 2)                                                        \
    ESRNN_STEP(QB, 0)                                                          \
    ESRNN_STEP(QB, 1)                                                          \
    ESRNN_STEP(QB, 2)                                                          \
    ESRNN_STEP(QB, 3)                                                          \
    ESRNN_STEP(QB, 4)                                                          \
    ESRNN_STEP(QB, 5)                                                          \
    ESRNN_STEP(QB, 6)                                                          \
    ++g;                                                                       \
  }

__global__ __launch_bounds__(64) void esrnn_main(
    const float* __restrict__ train,        // (720, B)
    const float* __restrict__ lev_sms,      // (B,)
    const float* __restrict__ seas_sms,     // (B,)
    const float* __restrict__ init_seas_in, // (B, 7)
    float* __restrict__ levs_out,           // (720, B)
    float* __restrict__ seas_out,           // (727, B)
    float* __restrict__ partial)            // (718, NW) per-wave partials
{
  int b = blockIdx.x * 64 + threadIdx.x;
  bool valid = (b < B_DIM);
  int bc = valid ? b : (B_DIM - 1);
  int lane = threadIdx.x;
  int wid = blockIdx.x;

  float lsm = 1.0f / (1.0f + __expf(-lev_sms[bc]));
  float ssm = 1.0f / (1.0f + __expf(-seas_sms[bc]));
  float olm = 1.0f - lsm;
  float osm = 1.0f - ssm;

  float is[7];
#pragma unroll
  for (int j = 0; j < 7; ++j) is[j] = __expf(init_seas_in[bc * 7 + j]);

  float seas0 = is[0];
  float x0 = train[bc];
  float lev = __fdividef(x0, seas0);

  if (valid) {
    __builtin_nontemporal_store(lev, &levs_out[b]);
#pragma unroll
    for (int j = 0; j < 7; ++j)
      __builtin_nontemporal_store(is[j], &seas_out[j * B_DIM + b]);
    __builtin_nontemporal_store(seas0, &seas_out[7 * B_DIM + b]);
  }

  float buf[7];
#pragma unroll
  for (int j = 0; j < 6; ++j) buf[j] = is[j + 1];
  buf[6] = seas0;

  float llev = __logf(lev);
  float pld = 0.0f;

  float xa[7], xb[7], xc[7];
  int g = 0;
  int t = 1;
  PREFETCH(xa, 0)
  PREFETCH(xb, 1)

  // 102 groups = 34 x 3-phase buffer rotation, prefetching 2 groups ahead.
  for (int k = 0; k < 34; ++k) {
    ESRNN_GROUP(xa, xc)
    ESRNN_GROUP(xb, xa)
    ESRNN_GROUP(xc, xb)
  }

  // tail: t = 715..719 in xa (group 102, 102 % 3 == 0), buf pos 0..4
  ESRNN_STEP(xa, 0)
  ESRNN_STEP(xa, 1)
  ESRNN_STEP(xa, 2)
  ESRNN_STEP(xa, 3)
  ESRNN_STEP(xa, 4)
}

__global__ __launch_bounds__(64) void esrnn_reduce2(
    const float* __restrict__ partial, float* __restrict__ msld) {
  int row = blockIdx.x;  // 0..717
  int lane = threadIdx.x;
  float s = 0.0f;
  for (int i = lane; i < NW; i += 64) s += partial[row * NW + i];
  float tot = dpp_sum64(s);
  if (lane == 63) msld[row] = tot * (1.0f / (float)B_DIM);
}

extern "C" void kernel_launch(void* const* d_in, const int* in_sizes, int n_in,
                              void* d_out, int out_size, void* d_ws,
                              size_t ws_size, hipStream_t stream) {
  const float* train = (const float*)d_in[0];
  const float* lev_sms = (const float*)d_in[1];
  const float* seas_sms = (const float*)d_in[2];
  const float* init_seas = (const float*)d_in[3];

  float* out = (float*)d_out;
  float* levs = out;
  float* seas = out + OFF_SEAS;
  float* msld = out + OFF_MSLD;
  float* partial = (float*)d_ws;  // 718*782*4 ~= 2.25 MB

  esrnn_main<<<NBLK, 64, 0, stream>>>(train, lev_sms, seas_sms, init_seas,
                                      levs, seas, partial);
  esrnn_reduce2<<<N_MSLD, 64, 0, stream>>>(partial, msld);
}